// Round 3
// baseline (400.770 us; speedup 1.0000x reference)
//
#include <hip/hip_runtime.h>

typedef unsigned short u16;
typedef __attribute__((ext_vector_type(8))) short bf16x8;
typedef __attribute__((ext_vector_type(4))) float f32x4;

// ---------- bf16 split helpers ----------
__device__ __forceinline__ u16 f2bf_rne(float f) {
  unsigned u = __float_as_uint(f);
  u += 0x7fffu + ((u >> 16) & 1u);
  return (u16)(u >> 16);
}
__device__ __forceinline__ float bf2f(u16 h) {
  return __uint_as_float(((unsigned)h) << 16);
}
__device__ __forceinline__ void split1(float v, u16& h, u16& l) {
  u16 hh = f2bf_rne(v);
  h = hh;
  l = f2bf_rne(v - bf2f(hh));
}

// ---------- global -> LDS async 16B ----------
__device__ __forceinline__ void gl16(const void* g, void* l) {
  __builtin_amdgcn_global_load_lds(
      (const __attribute__((address_space(1))) unsigned int*)g,
      (__attribute__((address_space(3))) unsigned int*)l,
      16, 0, 0);
}

// ---------- merged split-convert (x and Wqkv) ----------
__global__ void split_convert_all(const float4* __restrict__ x,
                                  ushort4* __restrict__ xhi, ushort4* __restrict__ xlo,
                                  const float4* __restrict__ wq,
                                  ushort4* __restrict__ wqh, ushort4* __restrict__ wql) {
  int i = blockIdx.x * 256 + threadIdx.x;
  const float4* src;
  ushort4 *dh, *dl;
  int idx;
  if (i < 3145728) { src = x; dh = xhi; dl = xlo; idx = i; }
  else if (i < 3588096) { src = wq; dh = wqh; dl = wql; idx = i - 3145728; }
  else return;
  float4 v = src[idx];
  ushort4 h, l;
  split1(v.x, h.x, l.x); split1(v.y, h.y, l.y);
  split1(v.z, h.z, l.z); split1(v.w, h.w, l.w);
  dh[idx] = h; dl[idx] = l;
}

// ---------- split-bf16 GEMM: C[M,N] = A[M,K] * B[N,K]^T ----------
// R8 = R3 structure + guide's T3 "minimum 2-phase" prefetch (the ONLY change).
// R6/R7 lesson: custom multi-barrier / counted-vmcnt schedules regressed
// (42/41% MfmaUtil vs R3's 52%). This is the verified minimal recipe instead:
//   stage(0); syncthreads;
//   for t: { stage(t+1, other buf); ds_read+MFMA from buf t; syncthreads; }
// One barrier per K-step (same barrier:MFMA ratio as R3), but the vmcnt(0)
// drain at the barrier now waits on loads issued a full compute phase
// (~1860 cyc/SIMD) earlier -> HBM latency hidden instead of exposed.
// BK=32 so the double buffer stays 64 KiB total -> 2 blocks/CU preserved.
// 128x128 tile, 4 waves (2x2), wave-tile 64x64 via 4x4 mfma_f32_16x16x32_bf16.
// 3 MFMAs per fragment pair: hi*hi + hi*lo + lo*hi (~2^-17 product error);
// k-accumulation order identical to R3 -> bit-identical numerics.
// Swizzle (32-u16 rows = 4 chunks of 16B): physical chunk p of row r holds
// logical chunk p ^ ((r>>1)&3); 16-lane reader groups hit 8 bank-quads with
// exactly 2 lanes each (2-way = free; verified 0 conflicts in R6). Staging
// pre-swizzles the per-lane GLOBAL source so the wave-uniform gl16 LDS
// destination stays linear (both-sides-or-neither rule).
// A has explicit row stride lda (u16 elems) so GEMM2 reads the interleaved
// hi/lo rows written in-place into the qkv region. B stride = K.
// B2 pair: rows with 2*tm0 >= M use Bhi2/Blo2 (per-batch folded weights in GEMM2).
__global__ __launch_bounds__(256, 2) void gemm_split_bt(
    const u16* __restrict__ Ahi, const u16* __restrict__ Alo, int lda,
    const u16* __restrict__ Bhi, const u16* __restrict__ Blo,
    const u16* __restrict__ Bhi2, const u16* __restrict__ Blo2,
    float* __restrict__ C, int M, int N, int K) {
  __shared__ __align__(16) u16 sAh[2][4096], sAl[2][4096];  // 128 rows x 32 u16
  __shared__ __align__(16) u16 sBh[2][4096], sBl[2][4096];
  const int tid = threadIdx.x;
  const int wave = tid >> 6;
  const int lane = tid & 63;
  const int tm0 = blockIdx.x * 128;
  const int tn0 = blockIdx.y * 128;
  const int wm = (wave & 1) * 64;
  const int wn = (wave >> 1) * 64;
  if (2 * tm0 >= M) { Bhi = Bhi2; Blo = Blo2; }

  // staging: per wave 8 gl16 per 32-k tile; each gl16 covers 16 rows
  // (64 B/row, 4 lanes/row). Wave owns rows [wave*32, wave*32+32).
  const int r4 = lane >> 2;                           // row within 16-row group
  const int sc = ((lane & 3) ^ ((r4 >> 1) & 3)) * 8;  // inverse-swizzled src chunk
  const int srow = wave * 32 + r4;
  const u16* gAh = Ahi + (size_t)(tm0 + srow) * lda + sc;
  const u16* gAl = Alo + (size_t)(tm0 + srow) * lda + sc;
  const u16* gBh = Bhi + (size_t)(tn0 + srow) * K + sc;
  const u16* gBl = Blo + (size_t)(tn0 + srow) * K + sc;
  const size_t rA = (size_t)16 * lda;  // +16 rows for second gl16
  const size_t rB = (size_t)16 * K;
  const int ldst = wave * 1024;  // u16 offset of wave's 32-row strip

  auto stage = [&](int t, int b) {
    const int kk = t << 5;
    gl16(gAh + kk, &sAh[b][ldst]);
    gl16(gAh + kk + rA, &sAh[b][ldst + 512]);
    gl16(gAl + kk, &sAl[b][ldst]);
    gl16(gAl + kk + rA, &sAl[b][ldst + 512]);
    gl16(gBh + kk, &sBh[b][ldst]);
    gl16(gBh + kk + rB, &sBh[b][ldst + 512]);
    gl16(gBl + kk, &sBl[b][ldst]);
    gl16(gBl + kk + rB, &sBl[b][ldst + 512]);
  };

  f32x4 acc[4][4] = {};
  const int fr = lane & 15;    // A/B fragment row (m or n within 16-tile)
  const int quad = lane >> 4;  // logical k-chunk (k = quad*8 + j)
  const int k0 = (quad ^ ((fr >> 1) & 3)) * 8;  // physical chunk * 8 u16
  const int nt = K >> 5;       // 24 for K=768

  stage(0, 0);
  __syncthreads();  // buf0 resident

  for (int t = 0; t < nt; ++t) {
    const int cb = t & 1;
    if (t + 1 < nt) stage(t + 1, cb ^ 1);  // prefetch; lands under this compute
    bf16x8 ah[4], al[4], bh[4], bl[4];
#pragma unroll
    for (int i = 0; i < 4; ++i) {
      ah[i] = *(const bf16x8*)&sAh[cb][(wm + i * 16 + fr) * 32 + k0];
      al[i] = *(const bf16x8*)&sAl[cb][(wm + i * 16 + fr) * 32 + k0];
      bh[i] = *(const bf16x8*)&sBh[cb][(wn + i * 16 + fr) * 32 + k0];
      bl[i] = *(const bf16x8*)&sBl[cb][(wn + i * 16 + fr) * 32 + k0];
    }
#pragma unroll
    for (int i = 0; i < 4; ++i)
#pragma unroll
      for (int j = 0; j < 4; ++j) {
        acc[i][j] = __builtin_amdgcn_mfma_f32_16x16x32_bf16(ah[i], bh[j], acc[i][j], 0, 0, 0);
        acc[i][j] = __builtin_amdgcn_mfma_f32_16x16x32_bf16(ah[i], bl[j], acc[i][j], 0, 0, 0);
        acc[i][j] = __builtin_amdgcn_mfma_f32_16x16x32_bf16(al[i], bh[j], acc[i][j], 0, 0, 0);
      }
    // drains this iter's ds_reads AND the prefetch for t+1; also guarantees
    // all waves are done reading buf cb before iter t+1 stages into it.
    __syncthreads();
  }

  // C/D layout: col = lane&15, row = (lane>>4)*4 + reg  (verified m89/m91)
  const int col = lane & 15;
  const int rowq = (lane >> 4) * 4;
#pragma unroll
  for (int i = 0; i < 4; ++i)
#pragma unroll
    for (int j = 0; j < 4; ++j) {
      size_t base = (size_t)(tm0 + wm + i * 16 + rowq) * N + (tn0 + wn + j * 16 + col);
#pragma unroll
      for (int r = 0; r < 4; ++r) C[base + (size_t)r * N] = acc[i][j][r];
    }
}

// ---------- fused dilated attention (+ column partial sums, split output IN PLACE) ----------
// One block per (b, i0): tokens T_j = i0 + 2048*j. Branches fold into a 4x4 matrix
// per head. Writes UNNORMALIZED output as bf16 hi/lo splits IN PLACE into the qkv
// region: row t's 9216-byte slot holds hi at u16 offset t*4608, lo at t*4608+768.
// Race-free: each block exclusively owns its 4 token rows and has them in LDS
// before the write phase. (R5 lesson: 16384x768 u16 = 25.17 MB per array — the
// separate-buffer layout overlapped and corrupted batch-0's lo. Size in BYTES.)
__global__ __launch_bounds__(256) void attn_dilated(const float* __restrict__ qkv,
                                                    u16* __restrict__ qk16,
                                                    float* __restrict__ Spart) {
  __shared__ float rows[4][2312];
  __shared__ float sc[12][16];
  __shared__ float Aw[12][16];
  const int t = threadIdx.x;
  const int i0 = blockIdx.x;  // 0..2047
  const int b = blockIdx.y;   // 0..1
  const size_t rowbase = (size_t)b * 8192 + i0;

  for (int idx = t; idx < 4 * 576; idx += 256) {
    int j = idx / 576, c4 = idx - j * 576;
    ((float4*)rows[j])[c4] = ((const float4*)(qkv + (rowbase + 2048 * j) * 2304))[c4];
  }
  __syncthreads();

  if (t < 192) {  // scores: q_j . k_jp / 8  (float4 LDS reads)
    int h = t >> 4, j = (t >> 2) & 3, jp = t & 3;
    const float4* q = (const float4*)&rows[j][h * 64];
    const float4* k = (const float4*)&rows[jp][768 + h * 64];
    float s = 0.f;
#pragma unroll
    for (int d = 0; d < 16; ++d) {
      float4 a = q[d], bb = k[d];
      s += a.x * bb.x + a.y * bb.y + a.z * bb.z + a.w * bb.w;
    }
    sc[h][(j << 2) | jp] = s * 0.125f;
  }
  __syncthreads();

  if (t < 48) {  // combine branch weights
    int h = t >> 2, j = t & 3;
    float s0 = sc[h][j * 4 + 0], s1 = sc[h][j * 4 + 1];
    float s2 = sc[h][j * 4 + 2], s3 = sc[h][j * 4 + 3];
    float m = fmaxf(fmaxf(s0, s1), fmaxf(s2, s3));
    float e0 = expf(s0 - m), e1 = expf(s1 - m), e2 = expf(s2 - m), e3 = expf(s3 - m);
    float inv = 1.f / (e0 + e1 + e2 + e3);
    float a[4] = {e0 * inv, e1 * inv, e2 * inv, e3 * inv};
    if ((i0 & 1) == 0) {
      int p = j ^ 2;
      float ss = sc[h][j * 4 + j], sx = sc[h][j * 4 + p];
      float mm = fmaxf(ss, sx);
      float es = expf(ss - mm), ex = expf(sx - mm);
      float iv = 1.f / (es + ex);
      a[j] += es * iv;
      a[p] += ex * iv;
    }
    if ((i0 & 3) == 0) a[j] += 1.f;
    Aw[h][j * 4 + 0] = a[0]; Aw[h][j * 4 + 1] = a[1];
    Aw[h][j * 4 + 2] = a[2]; Aw[h][j * 4 + 3] = a[3];
  }
  __syncthreads();

  float* sp = Spart + ((size_t)b * 64 + (i0 & 63)) * 768;
#pragma unroll
  for (int rep = 0; rep < 3; ++rep) {
    int cc = rep * 256 + t;  // 0..767
    int h = cc >> 6;
    float ps = 0.f;
#pragma unroll
    for (int j = 0; j < 4; ++j) {
      float v = 0.f;
#pragma unroll
      for (int jp = 0; jp < 4; ++jp) v = fmaf(Aw[h][(j << 2) | jp], rows[jp][1536 + cc], v);
      u16 h16, l16;
      split1(v, h16, l16);
      size_t base = (rowbase + 2048 * j) * 4608;  // u16 offset of row slot
      qk16[base + cc] = h16;
      qk16[base + 768 + cc] = l16;
      ps += v;
    }
    atomicAdd(&sp[cc], ps);
  }
}

// ---------- reduce 64 partial slots -> Sinv = 1/colsum ----------
__global__ void colred(const float* __restrict__ Spart, float* __restrict__ Sinv) {
  int i = blockIdx.x * 256 + threadIdx.x;  // 0..1535
  if (i >= 1536) return;
  int b = i / 768, c = i - b * 768;
  const float* p = Spart + (size_t)b * 64 * 768 + c;
  float s = 0.f;
#pragma unroll
  for (int g = 0; g < 64; ++g) s += p[g * 768];
  Sinv[i] = 1.0f / s;
}

// ---------- fold normalization into Wout: W_b[e,c] = Wout[e,c] * Sinv[b,c], split ----------
__global__ void scale_wout(const float4* __restrict__ Wout, const float* __restrict__ Sinv,
                           ushort4* __restrict__ wh0, ushort4* __restrict__ wl0,
                           ushort4* __restrict__ wh1, ushort4* __restrict__ wl1) {
  int i = blockIdx.x * 256 + threadIdx.x;  // 0..294911 (2 * 147456 float4)
  if (i >= 294912) return;
  int b = i / 147456;
  int r = i - b * 147456;           // float4 index within 768x768
  int c = (r % 192) * 4;            // column of first element
  const float* s = Sinv + b * 768 + c;
  float4 v = Wout[r];
  v.x *= s[0]; v.y *= s[1]; v.z *= s[2]; v.w *= s[3];
  ushort4 h, l;
  split1(v.x, h.x, l.x); split1(v.y, h.y, l.y);
  split1(v.z, h.z, l.z); split1(v.w, h.w, l.w);
  if (b == 0) { wh0[r] = h; wl0[r] = l; }
  else        { wh1[r] = h; wl1[r] = l; }
}

extern "C" void kernel_launch(void* const* d_in, const int* in_sizes, int n_in,
                              void* d_out, int out_size, void* d_ws, size_t ws_size,
                              hipStream_t stream) {
  (void)in_sizes; (void)n_in; (void)out_size; (void)ws_size;
  const float* x = (const float*)d_in[0];     // (2,8192,768)
  const float* Wqkv = (const float*)d_in[1];  // (2304,768)
  const float* Wout = (const float*)d_in[2];  // (768,768)
  float* out = (float*)d_out;                 // (2,8192,768) fp32 final result

  // workspace layout (bytes):
  //  [0, 151MB)       qkv fp32; attn rewrites it in place as split hi/lo rows
  //                   (u16 row stride 4608: hi at +0, lo at +768)
  //  [151MB, +25MB)   xhi  -> after GEMM1: Spart(384K) + Sinv(6K) + W_b splits (4x1.15MB)
  //  [176MB, +25MB)   xlo  (free after GEMM1)
  //  [201MB, +7MB)    wqh, wql
  char* w = (char*)d_ws;
  float* qkv = (float*)(w);
  u16* qk16 = (u16*)(w);
  size_t off = 150994944;
  u16* xhi = (u16*)(w + off);
  float* Spart = (float*)(w + off);              // 393,216 B (reuse of xhi)
  float* Sinv = (float*)(w + off + 393216);      // 6,144 B
  u16* wh0 = (u16*)(w + off + 400000);           // 1,179,648 B each
  u16* wl0 = (u16*)(w + off + 1579648);
  u16* wh1 = (u16*)(w + off + 2759296);
  u16* wl1 = (u16*)(w + off + 3938944);
  off += 25165824;
  u16* xlo = (u16*)(w + off); off += 25165824;
  u16* wqh = (u16*)(w + off); off += 3538944;
  u16* wql = (u16*)(w + off); off += 3538944;    // ~208 MB total (same as R4)

  // 1) split-convert x and Wqkv
  split_convert_all<<<dim3(14016), 256, 0, stream>>>(
      (const float4*)x, (ushort4*)xhi, (ushort4*)xlo,
      (const float4*)Wqkv, (ushort4*)wqh, (ushort4*)wql);

  // 2) qkv = x @ Wqkv^T   (M=16384, N=2304, K=768)
  gemm_split_bt<<<dim3(128, 18), 256, 0, stream>>>(xhi, xlo, 768, wqh, wql, wqh, wql,
                                                   qkv, 16384, 2304, 768);

  // 3) zero partial-sum slots (xhi free now), fused attention:
  //    reads fp32 qkv rows, writes unnormalized hi/lo splits in place + Spart
  hipMemsetAsync(Spart, 0, 393216, stream);
  attn_dilated<<<dim3(2048, 2), 256, 0, stream>>>(qkv, qk16, Spart);

  // 4) reduce partials -> Sinv
  colred<<<dim3(6), 256, 0, stream>>>(Spart, Sinv);

  // 5) fold 1/S into Wout per batch, split to bf16 hi/lo
  scale_wout<<<dim3(1152), 256, 0, stream>>>((const float4*)Wout, Sinv,
                                             (ushort4*)wh0, (ushort4*)wl0,
                                             (ushort4*)wh1, (ushort4*)wl1);

  // 6) out = no @ W_b^T   (M=16384, N=768, K=768; A strided in qkv region)
  gemm_split_bt<<<dim3(128, 6), 256, 0, stream>>>(qk16, qk16 + 768, 4608,
                                                  wh0, wl0, wh1, wl1,
                                                  out, 16384, 768, 768);
}

// Round 4
// 386.751 us; speedup vs baseline: 1.0362x; 1.0362x over previous
//
#include <hip/hip_runtime.h>

typedef unsigned short u16;
typedef __attribute__((ext_vector_type(8))) short bf16x8;
typedef __attribute__((ext_vector_type(16))) float f32x16;

// ---------- bf16 split helpers ----------
__device__ __forceinline__ u16 f2bf_rne(float f) {
  unsigned u = __float_as_uint(f);
  u += 0x7fffu + ((u >> 16) & 1u);
  return (u16)(u >> 16);
}
__device__ __forceinline__ float bf2f(u16 h) {
  return __uint_as_float(((unsigned)h) << 16);
}
__device__ __forceinline__ void split1(float v, u16& h, u16& l) {
  u16 hh = f2bf_rne(v);
  h = hh;
  l = f2bf_rne(v - bf2f(hh));
}

// ---------- global -> LDS async 16B ----------
__device__ __forceinline__ void gl16(const void* g, void* l) {
  __builtin_amdgcn_global_load_lds(
      (const __attribute__((address_space(1))) unsigned int*)g,
      (__attribute__((address_space(3))) unsigned int*)l,
      16, 0, 0);
}

// ---------- merged split-convert (x and Wqkv) ----------
__global__ void split_convert_all(const float4* __restrict__ x,
                                  ushort4* __restrict__ xhi, ushort4* __restrict__ xlo,
                                  const float4* __restrict__ wq,
                                  ushort4* __restrict__ wqh, ushort4* __restrict__ wql) {
  int i = blockIdx.x * 256 + threadIdx.x;
  const float4* src;
  ushort4 *dh, *dl;
  int idx;
  if (i < 3145728) { src = x; dh = xhi; dl = xlo; idx = i; }
  else if (i < 3588096) { src = wq; dh = wqh; dl = wql; idx = i - 3145728; }
  else return;
  float4 v = src[idx];
  ushort4 h, l;
  split1(v.x, h.x, l.x); split1(v.y, h.y, l.y);
  split1(v.z, h.z, l.z); split1(v.w, h.w, l.w);
  dh[idx] = h; dl[idx] = l;
}

// ---------- split-bf16 GEMM: C[M,N] = A[M,K] * B[N,K]^T ----------
// R9 = R3 structure EXACTLY (BK=64, single-buffered LDS, stage -> sync ->
// compute -> sync; 155 us / 52% MfmaUtil baseline), with ONE isolated change:
// the wave-tile uses mfma_f32_32x32x16_bf16 (2x2 C-tiles of 32x32) instead of
// 4x4 of 16x16x32. Same 64x64 wave tile, same ds_read bytes (32 b128/tile),
// HALF the MFMA instructions (48 vs 96 per 64-k tile) and 13% less matrix-pipe
// time per FLOP (m119: 2495 vs 2075 TF ceiling). R6/R7/R8 lesson: every
// sync-structure restructure (dbuf/counted-vmcnt/3-buf) regressed to ~40%
// MfmaUtil; the R3 structure is kept frozen from here on.
// 3 MFMAs per fragment pair: hi*hi + hi*lo + lo*hi (~2^-17 product error).
// LDS XOR swizzle (rows = 8 chunks of 16B): physical chunk p of row r holds
// logical chunk p ^ (r&7). 32x32 frag read: lane l reads row (l&31), logical
// chunk ks*2+(l>>5); per bank-quad exactly 8 lanes x 4B = 32B/bank -> the
// minimum 8 phases for a wave64 b128 read, i.e. conflict-free (R3 measured 0).
// A has explicit row stride lda (u16 elems) so GEMM2 reads the interleaved
// hi/lo rows written in-place into the qkv region. B stride = K.
// B2 pair: rows with 2*tm0 >= M use Bhi2/Blo2 (per-batch folded weights in GEMM2).
__global__ __launch_bounds__(256, 2) void gemm_split_bt(
    const u16* __restrict__ Ahi, const u16* __restrict__ Alo, int lda,
    const u16* __restrict__ Bhi, const u16* __restrict__ Blo,
    const u16* __restrict__ Bhi2, const u16* __restrict__ Blo2,
    float* __restrict__ C, int M, int N, int K) {
  __shared__ __align__(16) u16 sAh[128 * 64], sAl[128 * 64], sBh[128 * 64], sBl[128 * 64];
  const int tid = threadIdx.x;
  const int wave = tid >> 6;
  const int lane = tid & 63;
  const int tm0 = blockIdx.x * 128;
  const int tn0 = blockIdx.y * 128;
  const int wm = (wave & 1) * 64;
  const int wn = (wave >> 1) * 64;
  if (2 * tm0 >= M) { Bhi = Bhi2; Blo = Blo2; }

  // staging (R3 exact): per wave 4 gl16 per array; each covers 8 rows
  // (128 B/row, 8 lanes/row), source chunk pre-swizzled.
  const int srow = wave * 32 + (lane >> 3);
  const int c = lane & 7;
  const int scol = (c ^ ((lane >> 3) & 7)) * 8;  // XOR-swizzled source chunk
  const u16* gAh = Ahi + (size_t)(tm0 + srow) * lda + scol;
  const u16* gAl = Alo + (size_t)(tm0 + srow) * lda + scol;
  const u16* gBh = Bhi + (size_t)(tn0 + srow) * K + scol;
  const u16* gBl = Blo + (size_t)(tn0 + srow) * K + scol;
  u16* lAh = &sAh[wave * 32 * 64];
  u16* lAl = &sAl[wave * 32 * 64];
  u16* lBh = &sBh[wave * 32 * 64];
  u16* lBl = &sBl[wave * 32 * 64];
  const size_t rstepA = (size_t)8 * lda;  // 8 rows per gl16
  const size_t rstepB = (size_t)8 * K;

  f32x16 acc[2][2] = {};
  const int row = lane & 31;    // A/B fragment row (m or n within 32-tile)
  const int khalf = lane >> 5;  // 8-elem k-chunk within a 16-k step
  // per-lane physical chunk (u16 offset) for each of the 4 k-steps of a tile
  int pk[4];
#pragma unroll
  for (int ks = 0; ks < 4; ++ks) pk[ks] = ((ks * 2 + khalf) ^ (row & 7)) * 8;
  const int oA0 = (wm + row) * 64, oA1 = (wm + 32 + row) * 64;
  const int oB0 = (wn + row) * 64, oB1 = (wn + 32 + row) * 64;

  for (int kt = 0; kt < K; kt += 64) {
#pragma unroll
    for (int r = 0; r < 4; ++r) {
      gl16(gAh + kt + r * rstepA, lAh + r * 512);
      gl16(gAl + kt + r * rstepA, lAl + r * 512);
      gl16(gBh + kt + r * rstepB, lBh + r * 512);
      gl16(gBl + kt + r * rstepB, lBl + r * 512);
    }
    __syncthreads();
#pragma unroll
    for (int ks = 0; ks < 4; ++ks) {
      bf16x8 ah[2], al[2], bh[2], bl[2];
      ah[0] = *(const bf16x8*)&sAh[oA0 + pk[ks]];
      ah[1] = *(const bf16x8*)&sAh[oA1 + pk[ks]];
      al[0] = *(const bf16x8*)&sAl[oA0 + pk[ks]];
      al[1] = *(const bf16x8*)&sAl[oA1 + pk[ks]];
      bh[0] = *(const bf16x8*)&sBh[oB0 + pk[ks]];
      bh[1] = *(const bf16x8*)&sBh[oB1 + pk[ks]];
      bl[0] = *(const bf16x8*)&sBl[oB0 + pk[ks]];
      bl[1] = *(const bf16x8*)&sBl[oB1 + pk[ks]];
#pragma unroll
      for (int i = 0; i < 2; ++i)
#pragma unroll
        for (int j = 0; j < 2; ++j) {
          acc[i][j] = __builtin_amdgcn_mfma_f32_32x32x16_bf16(ah[i], bh[j], acc[i][j], 0, 0, 0);
          acc[i][j] = __builtin_amdgcn_mfma_f32_32x32x16_bf16(ah[i], bl[j], acc[i][j], 0, 0, 0);
          acc[i][j] = __builtin_amdgcn_mfma_f32_32x32x16_bf16(al[i], bh[j], acc[i][j], 0, 0, 0);
        }
    }
    __syncthreads();
  }

  // C/D layout for 32x32: col = lane&31, row = (reg&3) + 8*(reg>>2) + 4*(lane>>5)
  // (verified m74/m101)
  const int ccol = lane & 31;
  const int rbase = (lane >> 5) * 4;
#pragma unroll
  for (int i = 0; i < 2; ++i)
#pragma unroll
    for (int j = 0; j < 2; ++j) {
      size_t cb = (size_t)(tm0 + wm + i * 32 + rbase) * N + (tn0 + wn + j * 32 + ccol);
#pragma unroll
      for (int r = 0; r < 16; ++r) {
        size_t crow = (size_t)((r & 3) + 8 * (r >> 2));
        C[cb + crow * N] = acc[i][j][r];
      }
    }
}

// ---------- fused dilated attention (+ column partial sums, split output IN PLACE) ----------
// One block per (b, i0): tokens T_j = i0 + 2048*j. Branches fold into a 4x4 matrix
// per head. Writes UNNORMALIZED output as bf16 hi/lo splits IN PLACE into the qkv
// region: row t's 9216-byte slot holds hi at u16 offset t*4608, lo at t*4608+768.
// Race-free: each block exclusively owns its 4 token rows and has them in LDS
// before the write phase. (R5 lesson: 16384x768 u16 = 25.17 MB per array — the
// separate-buffer layout overlapped and corrupted batch-0's lo. Size in BYTES.)
__global__ __launch_bounds__(256) void attn_dilated(const float* __restrict__ qkv,
                                                    u16* __restrict__ qk16,
                                                    float* __restrict__ Spart) {
  __shared__ float rows[4][2312];
  __shared__ float sc[12][16];
  __shared__ float Aw[12][16];
  const int t = threadIdx.x;
  const int i0 = blockIdx.x;  // 0..2047
  const int b = blockIdx.y;   // 0..1
  const size_t rowbase = (size_t)b * 8192 + i0;

  for (int idx = t; idx < 4 * 576; idx += 256) {
    int j = idx / 576, c4 = idx - j * 576;
    ((float4*)rows[j])[c4] = ((const float4*)(qkv + (rowbase + 2048 * j) * 2304))[c4];
  }
  __syncthreads();

  if (t < 192) {  // scores: q_j . k_jp / 8  (float4 LDS reads)
    int h = t >> 4, j = (t >> 2) & 3, jp = t & 3;
    const float4* q = (const float4*)&rows[j][h * 64];
    const float4* k = (const float4*)&rows[jp][768 + h * 64];
    float s = 0.f;
#pragma unroll
    for (int d = 0; d < 16; ++d) {
      float4 a = q[d], bb = k[d];
      s += a.x * bb.x + a.y * bb.y + a.z * bb.z + a.w * bb.w;
    }
    sc[h][(j << 2) | jp] = s * 0.125f;
  }
  __syncthreads();

  if (t < 48) {  // combine branch weights
    int h = t >> 2, j = t & 3;
    float s0 = sc[h][j * 4 + 0], s1 = sc[h][j * 4 + 1];
    float s2 = sc[h][j * 4 + 2], s3 = sc[h][j * 4 + 3];
    float m = fmaxf(fmaxf(s0, s1), fmaxf(s2, s3));
    float e0 = expf(s0 - m), e1 = expf(s1 - m), e2 = expf(s2 - m), e3 = expf(s3 - m);
    float inv = 1.f / (e0 + e1 + e2 + e3);
    float a[4] = {e0 * inv, e1 * inv, e2 * inv, e3 * inv};
    if ((i0 & 1) == 0) {
      int p = j ^ 2;
      float ss = sc[h][j * 4 + j], sx = sc[h][j * 4 + p];
      float mm = fmaxf(ss, sx);
      float es = expf(ss - mm), ex = expf(sx - mm);
      float iv = 1.f / (es + ex);
      a[j] += es * iv;
      a[p] += ex * iv;
    }
    if ((i0 & 3) == 0) a[j] += 1.f;
    Aw[h][j * 4 + 0] = a[0]; Aw[h][j * 4 + 1] = a[1];
    Aw[h][j * 4 + 2] = a[2]; Aw[h][j * 4 + 3] = a[3];
  }
  __syncthreads();

  float* sp = Spart + ((size_t)b * 64 + (i0 & 63)) * 768;
#pragma unroll
  for (int rep = 0; rep < 3; ++rep) {
    int cc = rep * 256 + t;  // 0..767
    int h = cc >> 6;
    float ps = 0.f;
#pragma unroll
    for (int j = 0; j < 4; ++j) {
      float v = 0.f;
#pragma unroll
      for (int jp = 0; jp < 4; ++jp) v = fmaf(Aw[h][(j << 2) | jp], rows[jp][1536 + cc], v);
      u16 h16, l16;
      split1(v, h16, l16);
      size_t base = (rowbase + 2048 * j) * 4608;  // u16 offset of row slot
      qk16[base + cc] = h16;
      qk16[base + 768 + cc] = l16;
      ps += v;
    }
    atomicAdd(&sp[cc], ps);
  }
}

// ---------- reduce 64 partial slots -> Sinv = 1/colsum ----------
__global__ void colred(const float* __restrict__ Spart, float* __restrict__ Sinv) {
  int i = blockIdx.x * 256 + threadIdx.x;  // 0..1535
  if (i >= 1536) return;
  int b = i / 768, c = i - b * 768;
  const float* p = Spart + (size_t)b * 64 * 768 + c;
  float s = 0.f;
#pragma unroll
  for (int g = 0; g < 64; ++g) s += p[g * 768];
  Sinv[i] = 1.0f / s;
}

// ---------- fold normalization into Wout: W_b[e,c] = Wout[e,c] * Sinv[b,c], split ----------
__global__ void scale_wout(const float4* __restrict__ Wout, const float* __restrict__ Sinv,
                           ushort4* __restrict__ wh0, ushort4* __restrict__ wl0,
                           ushort4* __restrict__ wh1, ushort4* __restrict__ wl1) {
  int i = blockIdx.x * 256 + threadIdx.x;  // 0..294911 (2 * 147456 float4)
  if (i >= 294912) return;
  int b = i / 147456;
  int r = i - b * 147456;           // float4 index within 768x768
  int c = (r % 192) * 4;            // column of first element
  const float* s = Sinv + b * 768 + c;
  float4 v = Wout[r];
  v.x *= s[0]; v.y *= s[1]; v.z *= s[2]; v.w *= s[3];
  ushort4 h, l;
  split1(v.x, h.x, l.x); split1(v.y, h.y, l.y);
  split1(v.z, h.z, l.z); split1(v.w, h.w, l.w);
  if (b == 0) { wh0[r] = h; wl0[r] = l; }
  else        { wh1[r] = h; wl1[r] = l; }
}

extern "C" void kernel_launch(void* const* d_in, const int* in_sizes, int n_in,
                              void* d_out, int out_size, void* d_ws, size_t ws_size,
                              hipStream_t stream) {
  (void)in_sizes; (void)n_in; (void)out_size; (void)ws_size;
  const float* x = (const float*)d_in[0];     // (2,8192,768)
  const float* Wqkv = (const float*)d_in[1];  // (2304,768)
  const float* Wout = (const float*)d_in[2];  // (768,768)
  float* out = (float*)d_out;                 // (2,8192,768) fp32 final result

  // workspace layout (bytes):
  //  [0, 151MB)       qkv fp32; attn rewrites it in place as split hi/lo rows
  //                   (u16 row stride 4608: hi at +0, lo at +768)
  //  [151MB, +25MB)   xhi  -> after GEMM1: Spart(384K) + Sinv(6K) + W_b splits (4x1.15MB)
  //  [176MB, +25MB)   xlo  (free after GEMM1)
  //  [201MB, +7MB)    wqh, wql
  char* w = (char*)d_ws;
  float* qkv = (float*)(w);
  u16* qk16 = (u16*)(w);
  size_t off = 150994944;
  u16* xhi = (u16*)(w + off);
  float* Spart = (float*)(w + off);              // 393,216 B (reuse of xhi)
  float* Sinv = (float*)(w + off + 393216);      // 6,144 B
  u16* wh0 = (u16*)(w + off + 400000);           // 1,179,648 B each
  u16* wl0 = (u16*)(w + off + 1579648);
  u16* wh1 = (u16*)(w + off + 2759296);
  u16* wl1 = (u16*)(w + off + 3938944);
  off += 25165824;
  u16* xlo = (u16*)(w + off); off += 25165824;
  u16* wqh = (u16*)(w + off); off += 3538944;
  u16* wql = (u16*)(w + off); off += 3538944;    // ~208 MB total (same as R4)

  // 1) split-convert x and Wqkv
  split_convert_all<<<dim3(14016), 256, 0, stream>>>(
      (const float4*)x, (ushort4*)xhi, (ushort4*)xlo,
      (const float4*)Wqkv, (ushort4*)wqh, (ushort4*)wql);

  // 2) qkv = x @ Wqkv^T   (M=16384, N=2304, K=768)
  gemm_split_bt<<<dim3(128, 18), 256, 0, stream>>>(xhi, xlo, 768, wqh, wql, wqh, wql,
                                                   qkv, 16384, 2304, 768);

  // 3) zero partial-sum slots (xhi free now), fused attention:
  //    reads fp32 qkv rows, writes unnormalized hi/lo splits in place + Spart
  hipMemsetAsync(Spart, 0, 393216, stream);
  attn_dilated<<<dim3(2048, 2), 256, 0, stream>>>(qkv, qk16, Spart);

  // 4) reduce partials -> Sinv
  colred<<<dim3(6), 256, 0, stream>>>(Spart, Sinv);

  // 5) fold 1/S into Wout per batch, split to bf16 hi/lo
  scale_wout<<<dim3(1152), 256, 0, stream>>>((const float4*)Wout, Sinv,
                                             (ushort4*)wh0, (ushort4*)wl0,
                                             (ushort4*)wh1, (ushort4*)wl1);

  // 6) out = no @ W_b^T   (M=16384, N=768, K=768; A strided in qkv region)
  gemm_split_bt<<<dim3(128, 6), 256, 0, stream>>>(qk16, qk16 + 768, 4608,
                                                  wh0, wl0, wh1, wl1,
                                                  out, 16384, 768, 768);
}

// Round 5
// 383.771 us; speedup vs baseline: 1.0443x; 1.0078x over previous
//
#include <hip/hip_runtime.h>

typedef unsigned short u16;
typedef __attribute__((ext_vector_type(8))) short bf16x8;
typedef __attribute__((ext_vector_type(4))) float f32x4;

// ---------- bf16 split helpers ----------
__device__ __forceinline__ u16 f2bf_rne(float f) {
  unsigned u = __float_as_uint(f);
  u += 0x7fffu + ((u >> 16) & 1u);
  return (u16)(u >> 16);
}
__device__ __forceinline__ float bf2f(u16 h) {
  return __uint_as_float(((unsigned)h) << 16);
}
__device__ __forceinline__ void split1(float v, u16& h, u16& l) {
  u16 hh = f2bf_rne(v);
  h = hh;
  l = f2bf_rne(v - bf2f(hh));
}

// ---------- global -> LDS async 16B ----------
__device__ __forceinline__ void gl16(const void* g, void* l) {
  __builtin_amdgcn_global_load_lds(
      (const __attribute__((address_space(1))) unsigned int*)g,
      (__attribute__((address_space(3))) unsigned int*)l,
      16, 0, 0);
}

// ---------- merged split-convert (x and Wqkv) ----------
__global__ void split_convert_all(const float4* __restrict__ x,
                                  ushort4* __restrict__ xhi, ushort4* __restrict__ xlo,
                                  const float4* __restrict__ wq,
                                  ushort4* __restrict__ wqh, ushort4* __restrict__ wql) {
  int i = blockIdx.x * 256 + threadIdx.x;
  const float4* src;
  ushort4 *dh, *dl;
  int idx;
  if (i < 3145728) { src = x; dh = xhi; dl = xlo; idx = i; }
  else if (i < 3588096) { src = wq; dh = wqh; dl = wql; idx = i - 3145728; }
  else return;
  float4 v = src[idx];
  ushort4 h, l;
  split1(v.x, h.x, l.x); split1(v.y, h.y, l.y);
  split1(v.z, h.z, l.z); split1(v.w, h.w, l.w);
  dh[idx] = h; dl[idx] = l;
}

// ---------- split-bf16 GEMM: C[M,N] = A[M,K] * B[N,K]^T ----------
// R10 = R3 sync structure FROZEN (stage -> sync -> compute -> sync; the only
// structure that reached 52% MfmaUtil; R6/R7/R8 schedule restructures and R9's
// 32x32 shape all regressed). ONE isolated change vs R3: BK 64 -> 32 with a
// single 32 KiB LDS buffer -> 5 blocks/CU (was 2 at 64 KiB). Rationale (m114):
// the barrier drain is hidden by OTHER co-resident blocks' MFMA phases, not by
// intra-block ILP; at 2 blocks/CU each ~1.6Kcy drain faces only ~1.9Kcy of
// neighbor compute (-> 52% util); at 5 blocks/CU it faces ~4x that.
// Staging/reader addressing at BK=32 is byte-identical to R6/R8, which both
// MEASURED 0 bank conflicts and passed correctness (their regressions were the
// prefetch schedule, absent here). 16x16x32 MFMA kept (R9's 32x32 hit 14M
// conflicts: its row=lane&31 pattern breaks the HW's conflict-free sequencing;
// the fr=lane&15/quad=lane>>4 pattern gives each 8-lane group all distinct
// chunks).
// 3 MFMAs per fragment pair: hi*hi + hi*lo + lo*hi (~2^-17 product error);
// k-accumulation order identical to R3 -> numerics unchanged.
// Swizzle (32-u16 rows = 4 chunks of 16B): physical chunk p of row r holds
// logical chunk p ^ ((r>>1)&3); staging pre-swizzles the per-lane GLOBAL
// source so the wave-uniform gl16 LDS destination stays linear.
// A has explicit row stride lda (u16 elems) so GEMM2 reads the interleaved
// hi/lo rows written in-place into the qkv region. B stride = K.
// B2 pair: rows with 2*tm0 >= M use Bhi2/Blo2 (per-batch folded weights in GEMM2).
__global__ __launch_bounds__(256, 4) void gemm_split_bt(
    const u16* __restrict__ Ahi, const u16* __restrict__ Alo, int lda,
    const u16* __restrict__ Bhi, const u16* __restrict__ Blo,
    const u16* __restrict__ Bhi2, const u16* __restrict__ Blo2,
    float* __restrict__ C, int M, int N, int K) {
  __shared__ __align__(16) u16 sAh[4096], sAl[4096], sBh[4096], sBl[4096];  // 128x32 each
  const int tid = threadIdx.x;
  const int wave = tid >> 6;
  const int lane = tid & 63;
  const int tm0 = blockIdx.x * 128;
  const int tn0 = blockIdx.y * 128;
  const int wm = (wave & 1) * 64;
  const int wn = (wave >> 1) * 64;
  if (2 * tm0 >= M) { Bhi = Bhi2; Blo = Blo2; }

  // staging (R6-verified): per wave 8 gl16 per 32-k tile; each gl16 covers
  // 16 rows (64 B/row, 4 lanes/row). Wave owns rows [wave*32, wave*32+32).
  const int r4 = lane >> 2;                           // row within 16-row group
  const int sc = ((lane & 3) ^ ((r4 >> 1) & 3)) * 8;  // inverse-swizzled src chunk
  const int srow = wave * 32 + r4;
  const u16* gAh = Ahi + (size_t)(tm0 + srow) * lda + sc;
  const u16* gAl = Alo + (size_t)(tm0 + srow) * lda + sc;
  const u16* gBh = Bhi + (size_t)(tn0 + srow) * K + sc;
  const u16* gBl = Blo + (size_t)(tn0 + srow) * K + sc;
  const size_t rA = (size_t)16 * lda;  // +16 rows for second gl16
  const size_t rB = (size_t)16 * K;
  const int ldst = wave * 1024;  // u16 offset of wave's 32-row strip

  f32x4 acc[4][4] = {};
  const int fr = lane & 15;    // A/B fragment row (m or n within 16-tile)
  const int quad = lane >> 4;  // logical k-chunk (k = quad*8 + j)
  const int k0 = (quad ^ ((fr >> 1) & 3)) * 8;  // physical chunk * 8 u16

  for (int kt = 0; kt < K; kt += 32) {
    gl16(gAh + kt, &sAh[ldst]);
    gl16(gAh + kt + rA, &sAh[ldst + 512]);
    gl16(gAl + kt, &sAl[ldst]);
    gl16(gAl + kt + rA, &sAl[ldst + 512]);
    gl16(gBh + kt, &sBh[ldst]);
    gl16(gBh + kt + rB, &sBh[ldst + 512]);
    gl16(gBl + kt, &sBl[ldst]);
    gl16(gBl + kt + rB, &sBl[ldst + 512]);
    __syncthreads();
    bf16x8 ah[4], al[4], bh[4], bl[4];
#pragma unroll
    for (int i = 0; i < 4; ++i) {
      ah[i] = *(const bf16x8*)&sAh[(wm + i * 16 + fr) * 32 + k0];
      al[i] = *(const bf16x8*)&sAl[(wm + i * 16 + fr) * 32 + k0];
      bh[i] = *(const bf16x8*)&sBh[(wn + i * 16 + fr) * 32 + k0];
      bl[i] = *(const bf16x8*)&sBl[(wn + i * 16 + fr) * 32 + k0];
    }
#pragma unroll
    for (int i = 0; i < 4; ++i)
#pragma unroll
      for (int j = 0; j < 4; ++j) {
        acc[i][j] = __builtin_amdgcn_mfma_f32_16x16x32_bf16(ah[i], bh[j], acc[i][j], 0, 0, 0);
        acc[i][j] = __builtin_amdgcn_mfma_f32_16x16x32_bf16(ah[i], bl[j], acc[i][j], 0, 0, 0);
        acc[i][j] = __builtin_amdgcn_mfma_f32_16x16x32_bf16(al[i], bh[j], acc[i][j], 0, 0, 0);
      }
    __syncthreads();
  }

  // C/D layout: col = lane&15, row = (lane>>4)*4 + reg  (verified m89/m91)
  const int col = lane & 15;
  const int rowq = (lane >> 4) * 4;
#pragma unroll
  for (int i = 0; i < 4; ++i)
#pragma unroll
    for (int j = 0; j < 4; ++j) {
      size_t base = (size_t)(tm0 + wm + i * 16 + rowq) * N + (tn0 + wn + j * 16 + col);
#pragma unroll
      for (int r = 0; r < 4; ++r) C[base + (size_t)r * N] = acc[i][j][r];
    }
}

// ---------- fused dilated attention (+ column partial sums, split output IN PLACE) ----------
// One block per (b, i0): tokens T_j = i0 + 2048*j. Branches fold into a 4x4 matrix
// per head. Writes UNNORMALIZED output as bf16 hi/lo splits IN PLACE into the qkv
// region: row t's 9216-byte slot holds hi at u16 offset t*4608, lo at t*4608+768.
// Race-free: each block exclusively owns its 4 token rows and has them in LDS
// before the write phase. (R5 lesson: 16384x768 u16 = 25.17 MB per array — the
// separate-buffer layout overlapped and corrupted batch-0's lo. Size in BYTES.)
__global__ __launch_bounds__(256) void attn_dilated(const float* __restrict__ qkv,
                                                    u16* __restrict__ qk16,
                                                    float* __restrict__ Spart) {
  __shared__ float rows[4][2312];
  __shared__ float sc[12][16];
  __shared__ float Aw[12][16];
  const int t = threadIdx.x;
  const int i0 = blockIdx.x;  // 0..2047
  const int b = blockIdx.y;   // 0..1
  const size_t rowbase = (size_t)b * 8192 + i0;

  for (int idx = t; idx < 4 * 576; idx += 256) {
    int j = idx / 576, c4 = idx - j * 576;
    ((float4*)rows[j])[c4] = ((const float4*)(qkv + (rowbase + 2048 * j) * 2304))[c4];
  }
  __syncthreads();

  if (t < 192) {  // scores: q_j . k_jp / 8  (float4 LDS reads)
    int h = t >> 4, j = (t >> 2) & 3, jp = t & 3;
    const float4* q = (const float4*)&rows[j][h * 64];
    const float4* k = (const float4*)&rows[jp][768 + h * 64];
    float s = 0.f;
#pragma unroll
    for (int d = 0; d < 16; ++d) {
      float4 a = q[d], bb = k[d];
      s += a.x * bb.x + a.y * bb.y + a.z * bb.z + a.w * bb.w;
    }
    sc[h][(j << 2) | jp] = s * 0.125f;
  }
  __syncthreads();

  if (t < 48) {  // combine branch weights
    int h = t >> 2, j = t & 3;
    float s0 = sc[h][j * 4 + 0], s1 = sc[h][j * 4 + 1];
    float s2 = sc[h][j * 4 + 2], s3 = sc[h][j * 4 + 3];
    float m = fmaxf(fmaxf(s0, s1), fmaxf(s2, s3));
    float e0 = expf(s0 - m), e1 = expf(s1 - m), e2 = expf(s2 - m), e3 = expf(s3 - m);
    float inv = 1.f / (e0 + e1 + e2 + e3);
    float a[4] = {e0 * inv, e1 * inv, e2 * inv, e3 * inv};
    if ((i0 & 1) == 0) {
      int p = j ^ 2;
      float ss = sc[h][j * 4 + j], sx = sc[h][j * 4 + p];
      float mm = fmaxf(ss, sx);
      float es = expf(ss - mm), ex = expf(sx - mm);
      float iv = 1.f / (es + ex);
      a[j] += es * iv;
      a[p] += ex * iv;
    }
    if ((i0 & 3) == 0) a[j] += 1.f;
    Aw[h][j * 4 + 0] = a[0]; Aw[h][j * 4 + 1] = a[1];
    Aw[h][j * 4 + 2] = a[2]; Aw[h][j * 4 + 3] = a[3];
  }
  __syncthreads();

  float* sp = Spart + ((size_t)b * 64 + (i0 & 63)) * 768;
#pragma unroll
  for (int rep = 0; rep < 3; ++rep) {
    int cc = rep * 256 + t;  // 0..767
    int h = cc >> 6;
    float ps = 0.f;
#pragma unroll
    for (int j = 0; j < 4; ++j) {
      float v = 0.f;
#pragma unroll
      for (int jp = 0; jp < 4; ++jp) v = fmaf(Aw[h][(j << 2) | jp], rows[jp][1536 + cc], v);
      u16 h16, l16;
      split1(v, h16, l16);
      size_t base = (rowbase + 2048 * j) * 4608;  // u16 offset of row slot
      qk16[base + cc] = h16;
      qk16[base + 768 + cc] = l16;
      ps += v;
    }
    atomicAdd(&sp[cc], ps);
  }
}

// ---------- reduce 64 partial slots -> Sinv = 1/colsum ----------
__global__ void colred(const float* __restrict__ Spart, float* __restrict__ Sinv) {
  int i = blockIdx.x * 256 + threadIdx.x;  // 0..1535
  if (i >= 1536) return;
  int b = i / 768, c = i - b * 768;
  const float* p = Spart + (size_t)b * 64 * 768 + c;
  float s = 0.f;
#pragma unroll
  for (int g = 0; g < 64; ++g) s += p[g * 768];
  Sinv[i] = 1.0f / s;
}

// ---------- fold normalization into Wout: W_b[e,c] = Wout[e,c] * Sinv[b,c], split ----------
__global__ void scale_wout(const float4* __restrict__ Wout, const float* __restrict__ Sinv,
                           ushort4* __restrict__ wh0, ushort4* __restrict__ wl0,
                           ushort4* __restrict__ wh1, ushort4* __restrict__ wl1) {
  int i = blockIdx.x * 256 + threadIdx.x;  // 0..294911 (2 * 147456 float4)
  if (i >= 294912) return;
  int b = i / 147456;
  int r = i - b * 147456;           // float4 index within 768x768
  int c = (r % 192) * 4;            // column of first element
  const float* s = Sinv + b * 768 + c;
  float4 v = Wout[r];
  v.x *= s[0]; v.y *= s[1]; v.z *= s[2]; v.w *= s[3];
  ushort4 h, l;
  split1(v.x, h.x, l.x); split1(v.y, h.y, l.y);
  split1(v.z, h.z, l.z); split1(v.w, h.w, l.w);
  if (b == 0) { wh0[r] = h; wl0[r] = l; }
  else        { wh1[r] = h; wl1[r] = l; }
}

extern "C" void kernel_launch(void* const* d_in, const int* in_sizes, int n_in,
                              void* d_out, int out_size, void* d_ws, size_t ws_size,
                              hipStream_t stream) {
  (void)in_sizes; (void)n_in; (void)out_size; (void)ws_size;
  const float* x = (const float*)d_in[0];     // (2,8192,768)
  const float* Wqkv = (const float*)d_in[1];  // (2304,768)
  const float* Wout = (const float*)d_in[2];  // (768,768)
  float* out = (float*)d_out;                 // (2,8192,768) fp32 final result

  // workspace layout (bytes):
  //  [0, 151MB)       qkv fp32; attn rewrites it in place as split hi/lo rows
  //                   (u16 row stride 4608: hi at +0, lo at +768)
  //  [151MB, +25MB)   xhi  -> after GEMM1: Spart(384K) + Sinv(6K) + W_b splits (4x1.15MB)
  //  [176MB, +25MB)   xlo  (free after GEMM1)
  //  [201MB, +7MB)    wqh, wql
  char* w = (char*)d_ws;
  float* qkv = (float*)(w);
  u16* qk16 = (u16*)(w);
  size_t off = 150994944;
  u16* xhi = (u16*)(w + off);
  float* Spart = (float*)(w + off);              // 393,216 B (reuse of xhi)
  float* Sinv = (float*)(w + off + 393216);      // 6,144 B
  u16* wh0 = (u16*)(w + off + 400000);           // 1,179,648 B each
  u16* wl0 = (u16*)(w + off + 1579648);
  u16* wh1 = (u16*)(w + off + 2759296);
  u16* wl1 = (u16*)(w + off + 3938944);
  off += 25165824;
  u16* xlo = (u16*)(w + off); off += 25165824;
  u16* wqh = (u16*)(w + off); off += 3538944;
  u16* wql = (u16*)(w + off); off += 3538944;    // ~208 MB total (same as R4)

  // 1) split-convert x and Wqkv
  split_convert_all<<<dim3(14016), 256, 0, stream>>>(
      (const float4*)x, (ushort4*)xhi, (ushort4*)xlo,
      (const float4*)Wqkv, (ushort4*)wqh, (ushort4*)wql);

  // 2) qkv = x @ Wqkv^T   (M=16384, N=2304, K=768)
  gemm_split_bt<<<dim3(128, 18), 256, 0, stream>>>(xhi, xlo, 768, wqh, wql, wqh, wql,
                                                   qkv, 16384, 2304, 768);

  // 3) zero partial-sum slots (xhi free now), fused attention:
  //    reads fp32 qkv rows, writes unnormalized hi/lo splits in place + Spart
  hipMemsetAsync(Spart, 0, 393216, stream);
  attn_dilated<<<dim3(2048, 2), 256, 0, stream>>>(qkv, qk16, Spart);

  // 4) reduce partials -> Sinv
  colred<<<dim3(6), 256, 0, stream>>>(Spart, Sinv);

  // 5) fold 1/S into Wout per batch, split to bf16 hi/lo
  scale_wout<<<dim3(1152), 256, 0, stream>>>((const float4*)Wout, Sinv,
                                             (ushort4*)wh0, (ushort4*)wl0,
                                             (ushort4*)wh1, (ushort4*)wl1);

  // 6) out = no @ W_b^T   (M=16384, N=768, K=768; A strided in qkv region)
  gemm_split_bt<<<dim3(128, 6), 256, 0, stream>>>(qk16, qk16 + 768, 4608,
                                                  wh0, wl0, wh1, wl1,
                                                  out, 16384, 768, 768);
}

// Round 7
// 383.633 us; speedup vs baseline: 1.0447x; 1.0004x over previous
//
#include <hip/hip_runtime.h>

typedef unsigned short u16;
typedef __attribute__((ext_vector_type(8))) short bf16x8;
typedef __attribute__((ext_vector_type(4))) float f32x4;

// ---------- bf16 split helpers ----------
__device__ __forceinline__ u16 f2bf_rne(float f) {
  unsigned u = __float_as_uint(f);
  u += 0x7fffu + ((u >> 16) & 1u);
  return (u16)(u >> 16);
}
__device__ __forceinline__ float bf2f(u16 h) {
  return __uint_as_float(((unsigned)h) << 16);
}
__device__ __forceinline__ void split1(float v, u16& h, u16& l) {
  u16 hh = f2bf_rne(v);
  h = hh;
  l = f2bf_rne(v - bf2f(hh));
}

// ---------- global -> LDS async 16B ----------
__device__ __forceinline__ void gl16(const void* g, void* l) {
  __builtin_amdgcn_global_load_lds(
      (const __attribute__((address_space(1))) unsigned int*)g,
      (__attribute__((address_space(3))) unsigned int*)l,
      16, 0, 0);
}

// ---------- merged split-convert (x and Wqkv) ----------
__global__ void split_convert_all(const float4* __restrict__ x,
                                  ushort4* __restrict__ xhi, ushort4* __restrict__ xlo,
                                  const float4* __restrict__ wq,
                                  ushort4* __restrict__ wqh, ushort4* __restrict__ wql) {
  int i = blockIdx.x * 256 + threadIdx.x;
  const float4* src;
  ushort4 *dh, *dl;
  int idx;
  if (i < 3145728) { src = x; dh = xhi; dl = xlo; idx = i; }
  else if (i < 3588096) { src = wq; dh = wqh; dl = wql; idx = i - 3145728; }
  else return;
  float4 v = src[idx];
  ushort4 h, l;
  split1(v.x, h.x, l.x); split1(v.y, h.y, l.y);
  split1(v.z, h.z, l.z); split1(v.w, h.w, l.w);
  dh[idx] = h; dl[idx] = l;
}

// ---------- split-bf16 GEMM: C[M,N] = A[M,K] * B[N,K]^T ----------
// R12 = R0/R3 proven kernel (155 us, 0 conflicts, 52% MfmaUtil) with two
// NON-schedule changes (R6-R11 lessons: sync-structure edits and cheaper
// numeric bases all fail; bf16 3-term is required — absmax scales ~3e4 x
// the split scheme's rel error via colsum cancellation):
//  1) template<BM>: BM=128 (GEMM1, byte-identical to R0) or BM=64 (GEMM2):
//     48 KB LDS -> 3 blocks/CU, grid (256,6)=1536 blocks = 2.0 FULL rounds
//     (the 128-tile GEMM2 ran 768 blocks at 2/CU = 1.5 rounds -> 25% tail idle).
//  2) bijective XCD swizzle (T1, m204 form; both grids %8==0): consecutive
//     physical blocks land on one XCD and share the B panel in its L2.
// 3 MFMAs per fragment pair: hi*hi + hi*lo + lo*hi (~2^-17 product error).
// LDS XOR swizzle: physical chunk p of row r holds logical chunk p ^ (r&7);
// 16-lane reader groups put exactly 2 lanes per bank-quad (2-way = free).
// A has explicit row stride lda (u16 elems) so GEMM2 reads the interleaved
// hi/lo rows written in-place into the qkv region. B stride = K.
// B2 pair: rows with 2*tm0 >= M use Bhi2/Blo2 (per-batch folded weights in GEMM2).
template <int BM>
__global__ __launch_bounds__(256, (BM == 128 ? 2 : 3)) void gemm_split_bt(
    const u16* __restrict__ Ahi, const u16* __restrict__ Alo, int lda,
    const u16* __restrict__ Bhi, const u16* __restrict__ Blo,
    const u16* __restrict__ Bhi2, const u16* __restrict__ Blo2,
    float* __restrict__ C, int M, int N, int K) {
  constexpr int MI = BM / 32;      // per-wave m 16-tiles (4 or 2)
  constexpr int AR = BM / 4;       // A rows staged per wave (32 or 16)
  constexpr int RA = AR / 8;       // A gl16 reps per array (4 or 2)
  __shared__ __align__(16) u16 sAh[BM * 64], sAl[BM * 64];
  __shared__ __align__(16) u16 sBh[128 * 64], sBl[128 * 64];
  const int tid = threadIdx.x;
  const int wave = tid >> 6;
  const int lane = tid & 63;

  // XCD-aware bijective remap: physical linear id -> tile id so that each
  // XCD (= lid%8) gets a contiguous chunk of x-fastest tile ids (shared B).
  const int gx = gridDim.x;
  const int nwg = gx * gridDim.y;          // 2304 / 1536: both %8 == 0
  int lid = blockIdx.y * gx + blockIdx.x;
  lid = (lid & 7) * (nwg >> 3) + (lid >> 3);
  const int tm0 = (lid % gx) * BM;
  const int tn0 = (lid / gx) * 128;

  const int wm = (wave & 1) * (BM / 2);
  const int wn = (wave >> 1) * 64;
  if (2 * tm0 >= M) { Bhi = Bhi2; Blo = Blo2; }

  // staging: 8 lanes/row (128 B/row), 8 rows per gl16, source chunk
  // pre-swizzled. A: RA gl16 per array (wave owns AR rows); B: 4 (32 rows).
  const int c = lane & 7;
  const int scol = (c ^ ((lane >> 3) & 7)) * 8;  // XOR-swizzled source chunk
  const int srowA = wave * AR + (lane >> 3);
  const int srowB = wave * 32 + (lane >> 3);
  const u16* gAh = Ahi + (size_t)(tm0 + srowA) * lda + scol;
  const u16* gAl = Alo + (size_t)(tm0 + srowA) * lda + scol;
  const u16* gBh = Bhi + (size_t)(tn0 + srowB) * K + scol;
  const u16* gBl = Blo + (size_t)(tn0 + srowB) * K + scol;
  u16* lAh = &sAh[wave * AR * 64];
  u16* lAl = &sAl[wave * AR * 64];
  u16* lBh = &sBh[wave * 32 * 64];
  u16* lBl = &sBl[wave * 32 * 64];
  const size_t rstepA = (size_t)8 * lda;  // 8 rows per gl16
  const size_t rstepB = (size_t)8 * K;

  f32x4 acc[MI][4] = {};
  const int fr = lane & 15;    // A/B fragment row (m or n within 16-tile)
  const int quad = lane >> 4;  // logical k-chunk within 32-k sub-block

  for (int kt = 0; kt < K; kt += 64) {
#pragma unroll
    for (int r = 0; r < 4; ++r) {
      if (r < RA) {
        gl16(gAh + kt + r * rstepA, lAh + r * 512);
        gl16(gAl + kt + r * rstepA, lAl + r * 512);
      }
      gl16(gBh + kt + r * rstepB, lBh + r * 512);
      gl16(gBl + kt + r * rstepB, lBl + r * 512);
    }
    __syncthreads();
    for (int subk = 0; subk < 2; ++subk) {
      const int k0 = ((subk * 4 + quad) ^ (fr & 7)) * 8;  // physical chunk * 8 u16
      bf16x8 ah[MI], al[MI], bh[4], bl[4];
#pragma unroll
      for (int i = 0; i < MI; ++i) {
        ah[i] = *(const bf16x8*)&sAh[(wm + i * 16 + fr) * 64 + k0];
        al[i] = *(const bf16x8*)&sAl[(wm + i * 16 + fr) * 64 + k0];
      }
#pragma unroll
      for (int j = 0; j < 4; ++j) {
        bh[j] = *(const bf16x8*)&sBh[(wn + j * 16 + fr) * 64 + k0];
        bl[j] = *(const bf16x8*)&sBl[(wn + j * 16 + fr) * 64 + k0];
      }
#pragma unroll
      for (int i = 0; i < MI; ++i)
#pragma unroll
        for (int j = 0; j < 4; ++j) {
          acc[i][j] = __builtin_amdgcn_mfma_f32_16x16x32_bf16(ah[i], bh[j], acc[i][j], 0, 0, 0);
          acc[i][j] = __builtin_amdgcn_mfma_f32_16x16x32_bf16(ah[i], bl[j], acc[i][j], 0, 0, 0);
          acc[i][j] = __builtin_amdgcn_mfma_f32_16x16x32_bf16(al[i], bh[j], acc[i][j], 0, 0, 0);
        }
    }
    __syncthreads();
  }

  // C/D layout: col = lane&15, row = (lane>>4)*4 + reg  (verified m89/m91)
  const int col = lane & 15;
  const int rowq = (lane >> 4) * 4;
#pragma unroll
  for (int i = 0; i < MI; ++i)
#pragma unroll
    for (int j = 0; j < 4; ++j) {
      size_t base = (size_t)(tm0 + wm + i * 16 + rowq) * N + (tn0 + wn + j * 16 + col);
#pragma unroll
      for (int r = 0; r < 4; ++r) C[base + (size_t)r * N] = acc[i][j][r];
    }
}

// ---------- fused dilated attention (+ column partial sums, split output IN PLACE) ----------
// One block per (b, i0): tokens T_j = i0 + 2048*j. Branches fold into a 4x4 matrix
// per head. Writes UNNORMALIZED output as bf16 hi/lo splits IN PLACE into the qkv
// region: row t's 9216-byte slot holds hi at u16 offset t*4608, lo at t*4608+768.
// Race-free: each block exclusively owns its 4 token rows and has them in LDS
// before the write phase. (R5 lesson: 16384x768 u16 = 25.17 MB per array — the
// separate-buffer layout overlapped and corrupted batch-0's lo. Size in BYTES.)
__global__ __launch_bounds__(256) void attn_dilated(const float* __restrict__ qkv,
                                                    u16* __restrict__ qk16,
                                                    float* __restrict__ Spart) {
  __shared__ float rows[4][2312];
  __shared__ float sc[12][16];
  __shared__ float Aw[12][16];
  const int t = threadIdx.x;
  const int i0 = blockIdx.x;  // 0..2047
  const int b = blockIdx.y;   // 0..1
  const size_t rowbase = (size_t)b * 8192 + i0;

  for (int idx = t; idx < 4 * 576; idx += 256) {
    int j = idx / 576, c4 = idx - j * 576;
    ((float4*)rows[j])[c4] = ((const float4*)(qkv + (rowbase + 2048 * j) * 2304))[c4];
  }
  __syncthreads();

  if (t < 192) {  // scores: q_j . k_jp / 8  (float4 LDS reads)
    int h = t >> 4, j = (t >> 2) & 3, jp = t & 3;
    const float4* q = (const float4*)&rows[j][h * 64];
    const float4* k = (const float4*)&rows[jp][768 + h * 64];
    float s = 0.f;
#pragma unroll
    for (int d = 0; d < 16; ++d) {
      float4 a = q[d], bb = k[d];
      s += a.x * bb.x + a.y * bb.y + a.z * bb.z + a.w * bb.w;
    }
    sc[h][(j << 2) | jp] = s * 0.125f;
  }
  __syncthreads();

  if (t < 48) {  // combine branch weights
    int h = t >> 2, j = t & 3;
    float s0 = sc[h][j * 4 + 0], s1 = sc[h][j * 4 + 1];
    float s2 = sc[h][j * 4 + 2], s3 = sc[h][j * 4 + 3];
    float m = fmaxf(fmaxf(s0, s1), fmaxf(s2, s3));
    float e0 = expf(s0 - m), e1 = expf(s1 - m), e2 = expf(s2 - m), e3 = expf(s3 - m);
    float inv = 1.f / (e0 + e1 + e2 + e3);
    float a[4] = {e0 * inv, e1 * inv, e2 * inv, e3 * inv};
    if ((i0 & 1) == 0) {
      int p = j ^ 2;
      float ss = sc[h][j * 4 + j], sx = sc[h][j * 4 + p];
      float mm = fmaxf(ss, sx);
      float es = expf(ss - mm), ex = expf(sx - mm);
      float iv = 1.f / (es + ex);
      a[j] += es * iv;
      a[p] += ex * iv;
    }
    if ((i0 & 3) == 0) a[j] += 1.f;
    Aw[h][j * 4 + 0] = a[0]; Aw[h][j * 4 + 1] = a[1];
    Aw[h][j * 4 + 2] = a[2]; Aw[h][j * 4 + 3] = a[3];
  }
  __syncthreads();

  float* sp = Spart + ((size_t)b * 64 + (i0 & 63)) * 768;
#pragma unroll
  for (int rep = 0; rep < 3; ++rep) {
    int cc = rep * 256 + t;  // 0..767
    int h = cc >> 6;
    float ps = 0.f;
#pragma unroll
    for (int j = 0; j < 4; ++j) {
      float v = 0.f;
#pragma unroll
      for (int jp = 0; jp < 4; ++jp) v = fmaf(Aw[h][(j << 2) | jp], rows[jp][1536 + cc], v);
      u16 h16, l16;
      split1(v, h16, l16);
      size_t base = (rowbase + 2048 * j) * 4608;  // u16 offset of row slot
      qk16[base + cc] = h16;
      qk16[base + 768 + cc] = l16;
      ps += v;
    }
    atomicAdd(&sp[cc], ps);
  }
}

// ---------- reduce 64 partial slots -> Sinv = 1/colsum ----------
__global__ void colred(const float* __restrict__ Spart, float* __restrict__ Sinv) {
  int i = blockIdx.x * 256 + threadIdx.x;  // 0..1535
  if (i >= 1536) return;
  int b = i / 768, c = i - b * 768;
  const float* p = Spart + (size_t)b * 64 * 768 + c;
  float s = 0.f;
#pragma unroll
  for (int g = 0; g < 64; ++g) s += p[g * 768];
  Sinv[i] = 1.0f / s;
}

// ---------- fold normalization into Wout: W_b[e,c] = Wout[e,c] * Sinv[b,c], split ----------
__global__ void scale_wout(const float4* __restrict__ Wout, const float* __restrict__ Sinv,
                           ushort4* __restrict__ wh0, ushort4* __restrict__ wl0,
                           ushort4* __restrict__ wh1, ushort4* __restrict__ wl1) {
  int i = blockIdx.x * 256 + threadIdx.x;  // 0..294911 (2 * 147456 float4)
  if (i >= 294912) return;
  int b = i / 147456;
  int r = i - b * 147456;           // float4 index within 768x768
  int c = (r % 192) * 4;            // column of first element
  const float* s = Sinv + b * 768 + c;
  float4 v = Wout[r];
  v.x *= s[0]; v.y *= s[1]; v.z *= s[2]; v.w *= s[3];
  ushort4 h, l;
  split1(v.x, h.x, l.x); split1(v.y, h.y, l.y);
  split1(v.z, h.z, l.z); split1(v.w, h.w, l.w);
  if (b == 0) { wh0[r] = h; wl0[r] = l; }
  else        { wh1[r] = h; wl1[r] = l; }
}

extern "C" void kernel_launch(void* const* d_in, const int* in_sizes, int n_in,
                              void* d_out, int out_size, void* d_ws, size_t ws_size,
                              hipStream_t stream) {
  (void)in_sizes; (void)n_in; (void)out_size; (void)ws_size;
  const float* x = (const float*)d_in[0];     // (2,8192,768)
  const float* Wqkv = (const float*)d_in[1];  // (2304,768)
  const float* Wout = (const float*)d_in[2];  // (768,768)
  float* out = (float*)d_out;                 // (2,8192,768) fp32 final result

  // workspace layout (bytes):
  //  [0, 151MB)       qkv fp32; attn rewrites it in place as split hi/lo rows
  //                   (u16 row stride 4608: hi at +0, lo at +768)
  //  [151MB, +25MB)   xhi  -> after GEMM1: Spart(384K) + Sinv(6K) + W_b splits (4x1.15MB)
  //  [176MB, +25MB)   xlo  (free after GEMM1)
  //  [201MB, +7MB)    wqh, wql
  char* w = (char*)d_ws;
  float* qkv = (float*)(w);
  u16* qk16 = (u16*)(w);
  size_t off = 150994944;
  u16* xhi = (u16*)(w + off);
  float* Spart = (float*)(w + off);              // 393,216 B (reuse of xhi)
  float* Sinv = (float*)(w + off + 393216);      // 6,144 B
  u16* wh0 = (u16*)(w + off + 400000);           // 1,179,648 B each
  u16* wl0 = (u16*)(w + off + 1579648);
  u16* wh1 = (u16*)(w + off + 2759296);
  u16* wl1 = (u16*)(w + off + 3938944);
  off += 25165824;
  u16* xlo = (u16*)(w + off); off += 25165824;
  u16* wqh = (u16*)(w + off); off += 3538944;
  u16* wql = (u16*)(w + off); off += 3538944;    // ~208 MB total (same as R4)

  // 1) split-convert x and Wqkv
  split_convert_all<<<dim3(14016), 256, 0, stream>>>(
      (const float4*)x, (ushort4*)xhi, (ushort4*)xlo,
      (const float4*)Wqkv, (ushort4*)wqh, (ushort4*)wql);

  // 2) qkv = x @ Wqkv^T   (M=16384, N=2304, K=768)  [BM=128, 2304 blocks]
  gemm_split_bt<128><<<dim3(128, 18), 256, 0, stream>>>(xhi, xlo, 768, wqh, wql, wqh, wql,
                                                        qkv, 16384, 2304, 768);

  // 3) zero partial-sum slots (xhi free now), fused attention:
  //    reads fp32 qkv rows, writes unnormalized hi/lo splits in place + Spart
  hipMemsetAsync(Spart, 0, 393216, stream);
  attn_dilated<<<dim3(2048, 2), 256, 0, stream>>>(qkv, qk16, Spart);

  // 4) reduce partials -> Sinv
  colred<<<dim3(6), 256, 0, stream>>>(Spart, Sinv);

  // 5) fold 1/S into Wout per batch, split to bf16 hi/lo
  scale_wout<<<dim3(1152), 256, 0, stream>>>((const float4*)Wout, Sinv,
                                             (ushort4*)wh0, (ushort4*)wl0,
                                             (ushort4*)wh1, (ushort4*)wl1);

  // 6) out = no @ W_b^T   (M=16384, N=768, K=768; A strided in qkv region)
  //    BM=64: 1536 blocks at 3 blocks/CU = 2.0 full rounds (no 25% tail).
  gemm_split_bt<64><<<dim3(256, 6), 256, 0, stream>>>(qk16, qk16 + 768, 4608,
                                                      wh0, wl0, wh1, wl1,
                                                      out, 16384, 768, 768);
}

// Round 8
// 363.525 us; speedup vs baseline: 1.1025x; 1.0553x over previous
//
#include <hip/hip_runtime.h>

typedef unsigned short u16;
typedef __attribute__((ext_vector_type(8))) short bf16x8;
typedef __attribute__((ext_vector_type(4))) float f32x4;

// ---------- bf16 split helpers ----------
__device__ __forceinline__ u16 f2bf_rne(float f) {
  unsigned u = __float_as_uint(f);
  u += 0x7fffu + ((u >> 16) & 1u);
  return (u16)(u >> 16);
}
__device__ __forceinline__ float bf2f(u16 h) {
  return __uint_as_float(((unsigned)h) << 16);
}
__device__ __forceinline__ void split1(float v, u16& h, u16& l) {
  u16 hh = f2bf_rne(v);
  h = hh;
  l = f2bf_rne(v - bf2f(hh));
}

// ---------- global -> LDS async 16B ----------
__device__ __forceinline__ void gl16(const void* g, void* l) {
  __builtin_amdgcn_global_load_lds(
      (const __attribute__((address_space(1))) unsigned int*)g,
      (__attribute__((address_space(3))) unsigned int*)l,
      16, 0, 0);
}

// ---------- merged split-convert (x and Wqkv) ----------
__global__ void split_convert_all(const float4* __restrict__ x,
                                  ushort4* __restrict__ xhi, ushort4* __restrict__ xlo,
                                  const float4* __restrict__ wq,
                                  ushort4* __restrict__ wqh, ushort4* __restrict__ wql) {
  int i = blockIdx.x * 256 + threadIdx.x;
  const float4* src;
  ushort4 *dh, *dl;
  int idx;
  if (i < 3145728) { src = x; dh = xhi; dl = xlo; idx = i; }
  else if (i < 3588096) { src = wq; dh = wqh; dl = wql; idx = i - 3145728; }
  else return;
  float4 v = src[idx];
  ushort4 h, l;
  split1(v.x, h.x, l.x); split1(v.y, h.y, l.y);
  split1(v.z, h.z, l.z); split1(v.w, h.w, l.w);
  dh[idx] = h; dl[idx] = l;
}

// ---------- split-bf16 GEMM: C[M,N] = A[M,K] * B[N,K]^T ----------
// R13 = R0/R3 proven kernel with ONE surviving change from R12:
// template<BM> so GEMM2 uses BM=64 (48 KB LDS -> 3 blocks/CU; grid (256,6) =
// 1536 blocks = exactly 2.0 occupancy rounds, eliminating the 25% idle tail
// the 128-tile GEMM2 had at 768 blocks / 1.5 rounds).
// R12's XCD swizzle is REVERTED: it tripled FETCH_SIZE (150->451 MB) and
// slowed GEMM1 12% — the default x-fastest order keeps co-temporal blocks in
// a narrow A-row band that L2/L3 absorb; per-XCD n-column chunks destroyed
// that temporal locality (8 desynchronized full passes over the 50 MB A).
// Closed axes (measured): sync-structure edits (R6/R7/R8), 32x32 shape (R9),
// BK=32 TLP (R10), cheaper split bases (R11: absmax ~ 3e4 x per-product rel
// err via colsum cancellation -> bf16 3-term at 2^-18 is required).
// 3 MFMAs per fragment pair: hi*hi + hi*lo + lo*hi.
// LDS XOR swizzle: physical chunk p of row r holds logical chunk p ^ (r&7);
// 16-lane reader groups put exactly 2 lanes per bank-quad (2-way = free).
// A has explicit row stride lda (u16 elems) so GEMM2 reads the interleaved
// hi/lo rows written in-place into the qkv region. B stride = K.
// B2 pair: rows with 2*tm0 >= M use Bhi2/Blo2 (per-batch folded weights in GEMM2).
template <int BM>
__global__ __launch_bounds__(256, (BM == 128 ? 2 : 3)) void gemm_split_bt(
    const u16* __restrict__ Ahi, const u16* __restrict__ Alo, int lda,
    const u16* __restrict__ Bhi, const u16* __restrict__ Blo,
    const u16* __restrict__ Bhi2, const u16* __restrict__ Blo2,
    float* __restrict__ C, int M, int N, int K) {
  constexpr int MI = BM / 32;      // per-wave m 16-tiles (4 or 2)
  constexpr int AR = BM / 4;       // A rows staged per wave (32 or 16)
  constexpr int RA = AR / 8;       // A gl16 reps per array (4 or 2)
  __shared__ __align__(16) u16 sAh[BM * 64], sAl[BM * 64];
  __shared__ __align__(16) u16 sBh[128 * 64], sBl[128 * 64];
  const int tid = threadIdx.x;
  const int wave = tid >> 6;
  const int lane = tid & 63;
  const int tm0 = blockIdx.x * BM;
  const int tn0 = blockIdx.y * 128;
  const int wm = (wave & 1) * (BM / 2);
  const int wn = (wave >> 1) * 64;
  if (2 * tm0 >= M) { Bhi = Bhi2; Blo = Blo2; }

  // staging: 8 lanes/row (128 B/row), 8 rows per gl16, source chunk
  // pre-swizzled. A: RA gl16 per array (wave owns AR rows); B: 4 (32 rows).
  const int c = lane & 7;
  const int scol = (c ^ ((lane >> 3) & 7)) * 8;  // XOR-swizzled source chunk
  const int srowA = wave * AR + (lane >> 3);
  const int srowB = wave * 32 + (lane >> 3);
  const u16* gAh = Ahi + (size_t)(tm0 + srowA) * lda + scol;
  const u16* gAl = Alo + (size_t)(tm0 + srowA) * lda + scol;
  const u16* gBh = Bhi + (size_t)(tn0 + srowB) * K + scol;
  const u16* gBl = Blo + (size_t)(tn0 + srowB) * K + scol;
  u16* lAh = &sAh[wave * AR * 64];
  u16* lAl = &sAl[wave * AR * 64];
  u16* lBh = &sBh[wave * 32 * 64];
  u16* lBl = &sBl[wave * 32 * 64];
  const size_t rstepA = (size_t)8 * lda;  // 8 rows per gl16
  const size_t rstepB = (size_t)8 * K;

  f32x4 acc[MI][4] = {};
  const int fr = lane & 15;    // A/B fragment row (m or n within 16-tile)
  const int quad = lane >> 4;  // logical k-chunk within 32-k sub-block

  for (int kt = 0; kt < K; kt += 64) {
#pragma unroll
    for (int r = 0; r < 4; ++r) {
      if (r < RA) {
        gl16(gAh + kt + r * rstepA, lAh + r * 512);
        gl16(gAl + kt + r * rstepA, lAl + r * 512);
      }
      gl16(gBh + kt + r * rstepB, lBh + r * 512);
      gl16(gBl + kt + r * rstepB, lBl + r * 512);
    }
    __syncthreads();
    for (int subk = 0; subk < 2; ++subk) {
      const int k0 = ((subk * 4 + quad) ^ (fr & 7)) * 8;  // physical chunk * 8 u16
      bf16x8 ah[MI], al[MI], bh[4], bl[4];
#pragma unroll
      for (int i = 0; i < MI; ++i) {
        ah[i] = *(const bf16x8*)&sAh[(wm + i * 16 + fr) * 64 + k0];
        al[i] = *(const bf16x8*)&sAl[(wm + i * 16 + fr) * 64 + k0];
      }
#pragma unroll
      for (int j = 0; j < 4; ++j) {
        bh[j] = *(const bf16x8*)&sBh[(wn + j * 16 + fr) * 64 + k0];
        bl[j] = *(const bf16x8*)&sBl[(wn + j * 16 + fr) * 64 + k0];
      }
#pragma unroll
      for (int i = 0; i < MI; ++i)
#pragma unroll
        for (int j = 0; j < 4; ++j) {
          acc[i][j] = __builtin_amdgcn_mfma_f32_16x16x32_bf16(ah[i], bh[j], acc[i][j], 0, 0, 0);
          acc[i][j] = __builtin_amdgcn_mfma_f32_16x16x32_bf16(ah[i], bl[j], acc[i][j], 0, 0, 0);
          acc[i][j] = __builtin_amdgcn_mfma_f32_16x16x32_bf16(al[i], bh[j], acc[i][j], 0, 0, 0);
        }
    }
    __syncthreads();
  }

  // C/D layout: col = lane&15, row = (lane>>4)*4 + reg  (verified m89/m91)
  const int col = lane & 15;
  const int rowq = (lane >> 4) * 4;
#pragma unroll
  for (int i = 0; i < MI; ++i)
#pragma unroll
    for (int j = 0; j < 4; ++j) {
      size_t base = (size_t)(tm0 + wm + i * 16 + rowq) * N + (tn0 + wn + j * 16 + col);
#pragma unroll
      for (int r = 0; r < 4; ++r) C[base + (size_t)r * N] = acc[i][j][r];
    }
}

// ---------- fused dilated attention (+ column partial sums, split output IN PLACE) ----------
// One block per (b, i0): tokens T_j = i0 + 2048*j. Branches fold into a 4x4 matrix
// per head. Writes UNNORMALIZED output as bf16 hi/lo splits IN PLACE into the qkv
// region: row t's 9216-byte slot holds hi at u16 offset t*4608, lo at t*4608+768.
// Race-free: each block exclusively owns its 4 token rows and has them in LDS
// before the write phase. (R5 lesson: 16384x768 u16 = 25.17 MB per array — the
// separate-buffer layout overlapped and corrupted batch-0's lo. Size in BYTES.)
__global__ __launch_bounds__(256) void attn_dilated(const float* __restrict__ qkv,
                                                    u16* __restrict__ qk16,
                                                    float* __restrict__ Spart) {
  __shared__ float rows[4][2312];
  __shared__ float sc[12][16];
  __shared__ float Aw[12][16];
  const int t = threadIdx.x;
  const int i0 = blockIdx.x;  // 0..2047
  const int b = blockIdx.y;   // 0..1
  const size_t rowbase = (size_t)b * 8192 + i0;

  for (int idx = t; idx < 4 * 576; idx += 256) {
    int j = idx / 576, c4 = idx - j * 576;
    ((float4*)rows[j])[c4] = ((const float4*)(qkv + (rowbase + 2048 * j) * 2304))[c4];
  }
  __syncthreads();

  if (t < 192) {  // scores: q_j . k_jp / 8  (float4 LDS reads)
    int h = t >> 4, j = (t >> 2) & 3, jp = t & 3;
    const float4* q = (const float4*)&rows[j][h * 64];
    const float4* k = (const float4*)&rows[jp][768 + h * 64];
    float s = 0.f;
#pragma unroll
    for (int d = 0; d < 16; ++d) {
      float4 a = q[d], bb = k[d];
      s += a.x * bb.x + a.y * bb.y + a.z * bb.z + a.w * bb.w;
    }
    sc[h][(j << 2) | jp] = s * 0.125f;
  }
  __syncthreads();

  if (t < 48) {  // combine branch weights
    int h = t >> 2, j = t & 3;
    float s0 = sc[h][j * 4 + 0], s1 = sc[h][j * 4 + 1];
    float s2 = sc[h][j * 4 + 2], s3 = sc[h][j * 4 + 3];
    float m = fmaxf(fmaxf(s0, s1), fmaxf(s2, s3));
    float e0 = expf(s0 - m), e1 = expf(s1 - m), e2 = expf(s2 - m), e3 = expf(s3 - m);
    float inv = 1.f / (e0 + e1 + e2 + e3);
    float a[4] = {e0 * inv, e1 * inv, e2 * inv, e3 * inv};
    if ((i0 & 1) == 0) {
      int p = j ^ 2;
      float ss = sc[h][j * 4 + j], sx = sc[h][j * 4 + p];
      float mm = fmaxf(ss, sx);
      float es = expf(ss - mm), ex = expf(sx - mm);
      float iv = 1.f / (es + ex);
      a[j] += es * iv;
      a[p] += ex * iv;
    }
    if ((i0 & 3) == 0) a[j] += 1.f;
    Aw[h][j * 4 + 0] = a[0]; Aw[h][j * 4 + 1] = a[1];
    Aw[h][j * 4 + 2] = a[2]; Aw[h][j * 4 + 3] = a[3];
  }
  __syncthreads();

  float* sp = Spart + ((size_t)b * 64 + (i0 & 63)) * 768;
#pragma unroll
  for (int rep = 0; rep < 3; ++rep) {
    int cc = rep * 256 + t;  // 0..767
    int h = cc >> 6;
    float ps = 0.f;
#pragma unroll
    for (int j = 0; j < 4; ++j) {
      float v = 0.f;
#pragma unroll
      for (int jp = 0; jp < 4; ++jp) v = fmaf(Aw[h][(j << 2) | jp], rows[jp][1536 + cc], v);
      u16 h16, l16;
      split1(v, h16, l16);
      size_t base = (rowbase + 2048 * j) * 4608;  // u16 offset of row slot
      qk16[base + cc] = h16;
      qk16[base + 768 + cc] = l16;
      ps += v;
    }
    atomicAdd(&sp[cc], ps);
  }
}

// ---------- reduce 64 partial slots -> Sinv = 1/colsum ----------
__global__ void colred(const float* __restrict__ Spart, float* __restrict__ Sinv) {
  int i = blockIdx.x * 256 + threadIdx.x;  // 0..1535
  if (i >= 1536) return;
  int b = i / 768, c = i - b * 768;
  const float* p = Spart + (size_t)b * 64 * 768 + c;
  float s = 0.f;
#pragma unroll
  for (int g = 0; g < 64; ++g) s += p[g * 768];
  Sinv[i] = 1.0f / s;
}

// ---------- fold normalization into Wout: W_b[e,c] = Wout[e,c] * Sinv[b,c], split ----------
__global__ void scale_wout(const float4* __restrict__ Wout, const float* __restrict__ Sinv,
                           ushort4* __restrict__ wh0, ushort4* __restrict__ wl0,
                           ushort4* __restrict__ wh1, ushort4* __restrict__ wl1) {
  int i = blockIdx.x * 256 + threadIdx.x;  // 0..294911 (2 * 147456 float4)
  if (i >= 294912) return;
  int b = i / 147456;
  int r = i - b * 147456;           // float4 index within 768x768
  int c = (r % 192) * 4;            // column of first element
  const float* s = Sinv + b * 768 + c;
  float4 v = Wout[r];
  v.x *= s[0]; v.y *= s[1]; v.z *= s[2]; v.w *= s[3];
  ushort4 h, l;
  split1(v.x, h.x, l.x); split1(v.y, h.y, l.y);
  split1(v.z, h.z, l.z); split1(v.w, h.w, l.w);
  if (b == 0) { wh0[r] = h; wl0[r] = l; }
  else        { wh1[r] = h; wl1[r] = l; }
}

extern "C" void kernel_launch(void* const* d_in, const int* in_sizes, int n_in,
                              void* d_out, int out_size, void* d_ws, size_t ws_size,
                              hipStream_t stream) {
  (void)in_sizes; (void)n_in; (void)out_size; (void)ws_size;
  const float* x = (const float*)d_in[0];     // (2,8192,768)
  const float* Wqkv = (const float*)d_in[1];  // (2304,768)
  const float* Wout = (const float*)d_in[2];  // (768,768)
  float* out = (float*)d_out;                 // (2,8192,768) fp32 final result

  // workspace layout (bytes):
  //  [0, 151MB)       qkv fp32; attn rewrites it in place as split hi/lo rows
  //                   (u16 row stride 4608: hi at +0, lo at +768)
  //  [151MB, +25MB)   xhi  -> after GEMM1: Spart(384K) + Sinv(6K) + W_b splits (4x1.15MB)
  //  [176MB, +25MB)   xlo  (free after GEMM1)
  //  [201MB, +7MB)    wqh, wql
  char* w = (char*)d_ws;
  float* qkv = (float*)(w);
  u16* qk16 = (u16*)(w);
  size_t off = 150994944;
  u16* xhi = (u16*)(w + off);
  float* Spart = (float*)(w + off);              // 393,216 B (reuse of xhi)
  float* Sinv = (float*)(w + off + 393216);      // 6,144 B
  u16* wh0 = (u16*)(w + off + 400000);           // 1,179,648 B each
  u16* wl0 = (u16*)(w + off + 1579648);
  u16* wh1 = (u16*)(w + off + 2759296);
  u16* wl1 = (u16*)(w + off + 3938944);
  off += 25165824;
  u16* xlo = (u16*)(w + off); off += 25165824;
  u16* wqh = (u16*)(w + off); off += 3538944;
  u16* wql = (u16*)(w + off); off += 3538944;    // ~208 MB total (same as R4)

  // 1) split-convert x and Wqkv
  split_convert_all<<<dim3(14016), 256, 0, stream>>>(
      (const float4*)x, (ushort4*)xhi, (ushort4*)xlo,
      (const float4*)Wqkv, (ushort4*)wqh, (ushort4*)wql);

  // 2) qkv = x @ Wqkv^T   (M=16384, N=2304, K=768)  [BM=128, proven R0 config]
  gemm_split_bt<128><<<dim3(128, 18), 256, 0, stream>>>(xhi, xlo, 768, wqh, wql, wqh, wql,
                                                        qkv, 16384, 2304, 768);

  // 3) zero partial-sum slots (xhi free now), fused attention:
  //    reads fp32 qkv rows, writes unnormalized hi/lo splits in place + Spart
  hipMemsetAsync(Spart, 0, 393216, stream);
  attn_dilated<<<dim3(2048, 2), 256, 0, stream>>>(qkv, qk16, Spart);

  // 4) reduce partials -> Sinv
  colred<<<dim3(6), 256, 0, stream>>>(Spart, Sinv);

  // 5) fold 1/S into Wout per batch, split to bf16 hi/lo
  scale_wout<<<dim3(1152), 256, 0, stream>>>((const float4*)Wout, Sinv,
                                             (ushort4*)wh0, (ushort4*)wl0,
                                             (ushort4*)wh1, (ushort4*)wl1);

  // 6) out = no @ W_b^T   (M=16384, N=768, K=768; A strided in qkv region)
  //    BM=64: 1536 blocks at 3 blocks/CU = 2.0 full rounds (no 25% tail).
  gemm_split_bt<64><<<dim3(256, 6), 256, 0, stream>>>(qk16, qk16 + 768, 4608,
                                                      wh0, wl0, wh1, wl1,
                                                      out, 16384, 768, 768);
}